// Round 1
// baseline (101.791 us; speedup 1.0000x reference)
//
#include <hip/hip_runtime.h>
#include <hip/hip_bf16.h>

// ---------------------------------------------------------------------------
// Diagonal-covariance GMM log-likelihoods as one bf16 MFMA GEMM + bias:
//   out[m,k] = sum_f [ x^2 * (-0.5/cov) + x * (mu/cov) ] + bias[k]
//   bias[k]  = -0.5*D*log(2pi) - 0.5*sum log cov - 0.5*sum mu^2/cov
// GEMM: M=16384, N=512 (padded from 500), K2=2048 (interleaved x^2/x pairs)
// ---------------------------------------------------------------------------

typedef __attribute__((ext_vector_type(8))) __bf16 bf16x8;
typedef __attribute__((ext_vector_type(4))) float  f32x4;

#define LOG_2PI 1.837877066409345339082f

constexpr int M_TOT = 16384;   // B*T
constexpr int F_DIM = 1024;
constexpr int K_GMM = 500;
constexpr int N_PAD = 512;

constexpr int BM  = 128;
constexpr int BN  = 128;
constexpr int BKF = 32;              // K-step in floats (=> 64 bf16 along K2)
constexpr int NIT = F_DIM / BKF;     // 32 K-steps

// pack (bf16(x*x), bf16(x)) into one dword: low16 = x^2 (even K2 slot), hi16 = x
__device__ __forceinline__ unsigned pack_sq_x(float x) {
    __hip_bfloat162 h = __float22bfloat162_rn(make_float2(x * x, x));
    union { __hip_bfloat162 h; unsigned u; } cv;
    cv.h = h;
    return cv.u;
}

// ---------------------------------------------------------------------------
// prep: W[k][2f] = bf16(-0.5/cov), W[k][2f+1] = bf16(mu/cov); bias[k] in fp32.
// Rows k in [500,512) are zeroed (padding), bias=0 there.
// ---------------------------------------------------------------------------
__global__ __launch_bounds__(256) void prep_w_kernel(
    const float* __restrict__ mu, const float* __restrict__ cov,
    unsigned* __restrict__ Wb, float* __restrict__ bias)
{
    const int k = blockIdx.x;
    const int t = threadIdx.x;
    float sl = 0.f, sq = 0.f;
    if (k < K_GMM) {
        #pragma unroll
        for (int j = 0; j < 4; ++j) {
            const int f   = t + j * 256;
            const float c = cov[k * F_DIM + f];
            const float m = mu[k * F_DIM + f];
            const float ic = 1.0f / c;
            __hip_bfloat162 h = __float22bfloat162_rn(make_float2(-0.5f * ic, m * ic));
            union { __hip_bfloat162 h; unsigned u; } cv; cv.h = h;
            Wb[k * F_DIM + f] = cv.u;
            sl += logf(c);
            sq += m * m * ic;
        }
    } else {
        #pragma unroll
        for (int j = 0; j < 4; ++j) Wb[k * F_DIM + t + j * 256] = 0u;
    }
    #pragma unroll
    for (int off = 32; off > 0; off >>= 1) {
        sl += __shfl_down(sl, off, 64);
        sq += __shfl_down(sq, off, 64);
    }
    __shared__ float red[8];
    if ((t & 63) == 0) { red[(t >> 6) * 2] = sl; red[(t >> 6) * 2 + 1] = sq; }
    __syncthreads();
    if (t == 0) {
        const float SL = red[0] + red[2] + red[4] + red[6];
        const float SQ = red[1] + red[3] + red[5] + red[7];
        bias[k] = (k < K_GMM)
                ? (-0.5f * (F_DIM * LOG_2PI) - 0.5f * SL - 0.5f * SQ) : 0.f;
    }
}

// ---------------------------------------------------------------------------
// GEMM: 128x128 tile, 4 waves (2x2, 64x64 each), mfma_f32_16x16x32_bf16.
// A-side: X fp32 -> regs -> (x^2, x) bf16 pairs -> LDS.  B-side: Wb bf16 -> regs -> LDS.
// One-iteration register prefetch; 2 barriers per K-step (m97 structure).
// Block mapping: m_tile = bid&127, n_tile = bid>>7 => all 4 n-tiles of an
// m-tile share bid%8 (same XCD) so the X panel is read from HBM once.
// ---------------------------------------------------------------------------
__global__ __launch_bounds__(256, 3) void gemm_kernel(
    const float* __restrict__ X, const unsigned* __restrict__ Wb,
    const float* __restrict__ bias, float* __restrict__ out)
{
    __shared__ __align__(16) unsigned short As[BM * 64];  // 128 rows x 64 bf16 = 16 KiB
    __shared__ __align__(16) unsigned short Bs[BN * 64];  // 16 KiB

    const int bid    = blockIdx.x;
    const int m_base = (bid & 127) * BM;
    const int n_base = (bid >> 7) * BN;

    const int tid  = threadIdx.x;
    const int lane = tid & 63;
    const int wv   = tid >> 6;
    const int wr   = (wv >> 1) * 64;   // wave's row block in tile
    const int wc   = (wv & 1) * 64;    // wave's col block in tile
    const int hi   = lane >> 4;        // 0..3
    const int lo   = lane & 15;

    const int srow = tid >> 3;         // staging row (0..31, +i*32)
    const int scol = tid & 7;          // staging 16B chunk in 128B row

    const float4* Xv = reinterpret_cast<const float4*>(X);
    const uint4*  Wv = reinterpret_cast<const uint4*>(Wb);

    f32x4 acc[4][4];
    #pragma unroll
    for (int a = 0; a < 4; ++a)
        #pragma unroll
        for (int b = 0; b < 4; ++b)
            acc[a][b] = (f32x4){0.f, 0.f, 0.f, 0.f};

    float4 a_reg[4];
    uint4  b_reg[4];
    #pragma unroll
    for (int i = 0; i < 4; ++i) {
        a_reg[i] = Xv[(m_base + srow + i * 32) * (F_DIM / 4) + scol];
        b_reg[i] = Wv[(n_base + srow + i * 32) * (F_DIM / 4) + scol];
    }

    for (int it = 0; it < NIT; ++it) {
        __syncthreads();   // previous iteration's LDS reads complete
        #pragma unroll
        for (int i = 0; i < 4; ++i) {
            const float4 av = a_reg[i];
            uint4 wa;
            wa.x = pack_sq_x(av.x);
            wa.y = pack_sq_x(av.y);
            wa.z = pack_sq_x(av.z);
            wa.w = pack_sq_x(av.w);
            *reinterpret_cast<uint4*>(&As[tid * 8 + i * 2048]) = wa;
            *reinterpret_cast<uint4*>(&Bs[tid * 8 + i * 2048]) = b_reg[i];
        }
        __syncthreads();   // staging visible
        __builtin_amdgcn_sched_barrier(0);  // keep prefetch below the barrier

        if (it + 1 < NIT) {   // prefetch next K-step; lands during the MFMAs
            const int kf4 = (it + 1) * (BKF / 4);
            #pragma unroll
            for (int i = 0; i < 4; ++i) {
                a_reg[i] = Xv[(m_base + srow + i * 32) * (F_DIM / 4) + kf4 + scol];
                b_reg[i] = Wv[(n_base + srow + i * 32) * (F_DIM / 4) + kf4 + scol];
            }
        }

        #pragma unroll
        for (int c = 0; c < 2; ++c) {   // two K=32 chunks per K-step
            bf16x8 af[4], bfr[4];
            #pragma unroll
            for (int a = 0; a < 4; ++a)
                af[a] = *reinterpret_cast<const bf16x8*>(
                    &As[(wr + a * 16 + lo) * 64 + c * 32 + hi * 8]);
            #pragma unroll
            for (int b = 0; b < 4; ++b)
                bfr[b] = *reinterpret_cast<const bf16x8*>(
                    &Bs[(wc + b * 16 + lo) * 64 + c * 32 + hi * 8]);
            #pragma unroll
            for (int a = 0; a < 4; ++a)
                #pragma unroll
                for (int b = 0; b < 4; ++b)
                    acc[a][b] = __builtin_amdgcn_mfma_f32_16x16x32_bf16(
                        af[a], bfr[b], acc[a][b], 0, 0, 0);
        }
    }

    // Epilogue: D layout col = lane&15, row = (lane>>4)*4 + reg (verified m89/m91)
    #pragma unroll
    for (int b = 0; b < 4; ++b) {
        const int cn = n_base + wc + b * 16 + lo;
        if (cn >= K_GMM) continue;          // padded columns never stored
        const float bv = bias[cn];
        #pragma unroll
        for (int a = 0; a < 4; ++a) {
            const int r0 = m_base + wr + a * 16 + hi * 4;
            #pragma unroll
            for (int i = 0; i < 4; ++i)
                out[(size_t)(r0 + i) * K_GMM + cn] = acc[a][b][i] + bv;
        }
    }
}

extern "C" void kernel_launch(void* const* d_in, const int* in_sizes, int n_in,
                              void* d_out, int out_size, void* d_ws, size_t ws_size,
                              hipStream_t stream)
{
    (void)in_sizes; (void)n_in; (void)out_size; (void)ws_size;
    const float* X   = (const float*)d_in[0];
    const float* mu  = (const float*)d_in[1];
    const float* cov = (const float*)d_in[2];
    float* out = (float*)d_out;

    // workspace: Wb = 512*1024 dwords (2 MiB of bf16 pairs), then bias[512] f32
    unsigned* Wb   = (unsigned*)d_ws;
    float*    bias = (float*)((char*)d_ws + (size_t)N_PAD * F_DIM * 4);

    prep_w_kernel<<<dim3(N_PAD), dim3(256), 0, stream>>>(mu, cov, Wb, bias);
    gemm_kernel<<<dim3((M_TOT / BM) * (N_PAD / BN)), dim3(256), 0, stream>>>(X, Wb, bias, out);
}